// Round 2
// baseline (466.515 us; speedup 1.0000x reference)
//
#include <hip/hip_runtime.h>
#include <hip/hip_bf16.h>

#define EDGES 600000
#define DIN 128
#define DHID 256
#define DOUT 128

#define NCHUNK 37500            // EDGES / 16 (exact, no tail)
#define NBLK 512
#define THREADS 512
#define STRIDE 4096             // NBLK * 8 waves

// LDS map (bytes):
//   [0, 65536)        W1 frags  shortx8[(t*4+ks)*64 + lane]
//   [65536, 131072)   W2 frags  shortx4[(t*8+ot)*64 + lane]
//   [131072, 132096)  b1 (256 f32)
//   [132096, 132608)  b2 (128 f32)
#define W2_OFF 65536
#define B1_OFF 131072
#define B2_OFF 132096
#define LDS_BYTES 132608

typedef __attribute__((ext_vector_type(4))) float floatx4;
typedef __attribute__((ext_vector_type(4))) short shortx4;
typedef __attribute__((ext_vector_type(8))) short shortx8;

__device__ inline unsigned short f2bf_rne(float f) {
    union { float f; unsigned u; } v; v.f = f;
    unsigned r = v.u + 0x7FFFu + ((v.u >> 16) & 1u);
    return (unsigned short)(r >> 16);
}

// Pre-pass: convert W1/W2 fp32 -> bf16, swizzled fragment-major.
// W1s: frag (t,ks): 64 lanes x 8 bf16  (A-frag of 16x16x32: m=lane&15, k=q*8+j)
// W2s: frag (t,ot): 64 lanes x 4 bf16  (A-frag of 16x16x16: m=lane&15, k=q*4+j)
__global__ __launch_bounds__(256) void prep_kernel(
        const float* __restrict__ W1, const float* __restrict__ W2,
        unsigned short* __restrict__ ws) {
    int j = blockIdx.x * 256 + threadIdx.x;
    if (j < 4096) {                       // W1 frags: 16 t * 4 ks * 64 lanes
        int lane = j & 63, fs = j >> 6;
        int ks = fs & 3, t = fs >> 2;
        int hid = t * 16 + (lane & 15), q = lane >> 4;
        const float* src = W1 + hid * DIN + ks * 32 + q * 8;
        shortx8 v;
        #pragma unroll
        for (int i = 0; i < 8; ++i) v[i] = (short)f2bf_rne(src[i]);
        *((shortx8*)ws + j) = v;
    } else if (j < 12288) {               // W2 frags: 16 t * 8 ot * 64 lanes
        int j2 = j - 4096;
        int lane = j2 & 63, fs = j2 >> 6;
        int ot = fs & 7, t = fs >> 3;     // layout (t*8+ot)*64+lane
        int o = ot * 16 + (lane & 15), q = lane >> 4;
        const float* src = W2 + o * DHID + t * 16 + q * 4;
        shortx4 v;
        #pragma unroll
        for (int i = 0; i < 4; ++i) v[i] = (short)f2bf_rne(src[i]);
        *((shortx4*)(ws + 32768) + j2) = v;
    }
}

// Gather one 16-edge chunk's B-operand slice directly from x into registers.
// Lane (q,col): edge=col, floats [ks*32 + q*8 .. +7] of both endpoint rows.
#define GATHER(RAW, NA, NB) do {                                              \
    const float* pa_ = x + (size_t)(NA) * DIN + q * 8;                        \
    const float* pb_ = x + (size_t)(NB) * DIN + q * 8;                        \
    _Pragma("unroll")                                                         \
    for (int ks_ = 0; ks_ < 4; ++ks_) {                                       \
        RAW[ks_*4+0] = *(const float4*)(pa_ + ks_*32);                        \
        RAW[ks_*4+1] = *(const float4*)(pa_ + ks_*32 + 4);                    \
        RAW[ks_*4+2] = *(const float4*)(pb_ + ks_*32);                        \
        RAW[ks_*4+3] = *(const float4*)(pb_ + ks_*32 + 4);                    \
    }                                                                         \
} while (0)

// One chunk: convert RAW -> sfrag; prefetch ei (BEFORE gather, so the vmcnt
// wait on the index load doesn't drain the younger gather); issue next-next
// chunk's gather into the SAME buffer (depth-2 ping-pong); MFMA; nt-store.
#define BODY(RAW, NA_USE, NB_USE, NA_SET, NB_SET, C) do {                     \
    shortx8 sfrag[4];                                                         \
    _Pragma("unroll")                                                         \
    for (int ks_ = 0; ks_ < 4; ++ks_) {                                       \
        float4 u0 = RAW[ks_*4+0], u1 = RAW[ks_*4+1];                          \
        float4 v0 = RAW[ks_*4+2], v1 = RAW[ks_*4+3];                          \
        union { shortx8 s8; __hip_bfloat162 b[4]; } pk;                       \
        pk.b[0] = __float22bfloat162_rn(make_float2(u0.x+v0.x, u0.y+v0.y));   \
        pk.b[1] = __float22bfloat162_rn(make_float2(u0.z+v0.z, u0.w+v0.w));   \
        pk.b[2] = __float22bfloat162_rn(make_float2(u1.x+v1.x, u1.y+v1.y));   \
        pk.b[3] = __float22bfloat162_rn(make_float2(u1.z+v1.z, u1.w+v1.w));   \
        sfrag[ks_] = pk.s8;                                                   \
    }                                                                         \
    {                                                                         \
        const int cp_ = (C) + 3*STRIDE;                                       \
        if (cp_ < NCHUNK) {                                                   \
            const int ep_ = cp_*16 + col;                                     \
            NA_SET = ei[ep_]; NB_SET = ei[EDGES + ep_];                       \
        }                                                                     \
        const int cg_ = (C) + 2*STRIDE;                                       \
        if (cg_ < NCHUNK) GATHER(RAW, NA_USE, NB_USE);                        \
    }                                                                         \
    floatx4 acc2[8];                                                          \
    _Pragma("unroll")                                                         \
    for (int ot = 0; ot < 8; ++ot) acc2[ot] = b2l[ot*4];                      \
    _Pragma("unroll 1")                                                       \
    for (int t = 0; t < 16; ++t) {                                            \
        shortx8 a1[4];                                                        \
        _Pragma("unroll")                                                     \
        for (int ks_ = 0; ks_ < 4; ++ks_) a1[ks_] = w1l[(t*4+ks_)*64];        \
        floatx4 acc1 = b1l[t*4];                                              \
        _Pragma("unroll")                                                     \
        for (int ks_ = 0; ks_ < 4; ++ks_)                                     \
            acc1 = __builtin_amdgcn_mfma_f32_16x16x32_bf16(a1[ks_], sfrag[ks_], acc1, 0, 0, 0); \
        union { shortx4 s4; __hip_bfloat162 b[2]; } pk2;                      \
        pk2.b[0] = __float22bfloat162_rn(make_float2(fmaxf(acc1[0], 0.f), fmaxf(acc1[1], 0.f))); \
        pk2.b[1] = __float22bfloat162_rn(make_float2(fmaxf(acc1[2], 0.f), fmaxf(acc1[3], 0.f))); \
        const shortx4 hf = pk2.s4;                                            \
        _Pragma("unroll")                                                     \
        for (int ot = 0; ot < 8; ++ot) {                                      \
            shortx4 wb = w2l[(t*8+ot)*64];                                    \
            acc2[ot] = __builtin_amdgcn_mfma_f32_16x16x16bf16_1k(wb, hf, acc2[ot], 0, 0, 0); \
        }                                                                     \
    }                                                                         \
    {                                                                         \
        float* op_ = out + (size_t)((C)*16 + col) * DOUT + q * 4;             \
        _Pragma("unroll")                                                     \
        for (int ot = 0; ot < 8; ++ot) {                                      \
            floatx4 v_ = acc2[ot] * 0.5f;                                     \
            __builtin_nontemporal_store(v_, (floatx4*)(op_ + ot*16));         \
        }                                                                     \
    }                                                                         \
} while (0)

__global__ __launch_bounds__(512, 2) void gin_kernel(
        const float* __restrict__ x, const int* __restrict__ ei,
        const float* __restrict__ b1, const float* __restrict__ b2,
        const unsigned short* __restrict__ wsw,
        float* __restrict__ out) {
    extern __shared__ char smem[];
    const int tid = threadIdx.x;
    const int lane = tid & 63, q = lane >> 4, col = lane & 15;
    const int gw = blockIdx.x * 8 + (tid >> 6);   // < 4096 <= NCHUNK: valid

    int ch = gw;
    float4 rawA[16], rawB[16];
    int naP, nbP, naQ, nbQ;

    // ---- prologue ----
    {
        // weights -> LDS (131072 B = 8192 float4, 16 per thread)
        const float4* gsrc = (const float4*)wsw;
        #pragma unroll 4
        for (int it = 0; it < 16; ++it) {
            const int idx = it * 512 + tid;
            float4 v = gsrc[idx];
            *(float4*)(smem + (size_t)idx * 16) = v;
        }
        if (tid < 384) {
            float v = (tid < 256) ? b1[tid] : b2[tid - 256];
            *(float*)(smem + B1_OFF + tid * 4) = v;
        }
        // chunk0 gather
        const int e0 = ch * 16 + col;
        const int a0 = ei[e0], b0 = ei[EDGES + e0];
        GATHER(rawA, a0, b0);
        // chunk1 gather
        const int c1 = ch + STRIDE;
        if (c1 < NCHUNK) {
            const int e1 = c1 * 16 + col;
            const int a1v = ei[e1], b1v = ei[EDGES + e1];
            GATHER(rawB, a1v, b1v);
        }
        // ei prefetch for chunk2 (consumed by first BODY's gather)
        const int c2 = ch + 2 * STRIDE;
        if (c2 < NCHUNK) {
            const int e2 = c2 * 16 + col;
            naP = ei[e2]; nbP = ei[EDGES + e2];
        }
    }
    __syncthreads();   // weights ready; no barriers after this point

    const shortx8* w1l = (const shortx8*)smem + lane;
    const shortx4* w2l = (const shortx4*)(smem + W2_OFF) + lane;
    const floatx4* b1l = (const floatx4*)(smem + B1_OFF) + q;
    const floatx4* b2l = (const floatx4*)(smem + B2_OFF) + q;

    for (;;) {
        BODY(rawA, naP, nbP, naQ, nbQ, ch);
        if (ch + STRIDE >= NCHUNK) break;
        BODY(rawB, naQ, nbQ, naP, nbP, ch + STRIDE);
        if (ch + 2 * STRIDE >= NCHUNK) break;
        ch += 2 * STRIDE;
    }
}

extern "C" void kernel_launch(void* const* d_in, const int* in_sizes, int n_in,
                              void* d_out, int out_size, void* d_ws, size_t ws_size,
                              hipStream_t stream) {
    const float* x  = (const float*)d_in[0];
    const int*   ei = (const int*)d_in[1];     // edge_index as int32 per harness
    const float* W1 = (const float*)d_in[2];
    const float* b1 = (const float*)d_in[3];
    const float* W2 = (const float*)d_in[4];
    const float* b2 = (const float*)d_in[5];
    unsigned short* ws = (unsigned short*)d_ws;   // 64KB W1s + 64KB W2s

    static bool attr_done = false;
    if (!attr_done) {
        (void)hipFuncSetAttribute((const void*)gin_kernel,
                                  hipFuncAttributeMaxDynamicSharedMemorySize,
                                  LDS_BYTES);
        attr_done = true;
    }

    prep_kernel<<<48, 256, 0, stream>>>(W1, W2, ws);
    gin_kernel<<<NBLK, THREADS, LDS_BYTES, stream>>>(x, ei, b1, b2, ws, (float*)d_out);
}